// Round 2
// baseline (550.216 us; speedup 1.0000x reference)
//
#include <hip/hip_runtime.h>

// LayoutLMv2 self-attention, MI355X.  B=8 N=1024 H=16 D=64.
// fp32->bf16 converts, bias combine (log2e folded), mask->f32, bf16 MFMA QKV GEMM
// (q-scale*log2e folded), flash attention: 2 q-strips/wave, MAX-FREE log2-domain
// softmax (scores provably bounded ~2^15), bias folded into MFMA C-operand,
// ZERO LDS round-trip for P: the S^T MFMA consumes K rows in a permuted order
// chosen so its C-layout output IS the O-MFMA B-operand fragment, in-register.
// LDS = K/V double-buffer only (32KB) -> 5 blocks/CU. XCD-aware block decode
// gives bias 8x L2 reuse across batch and K/V 8x L2 reuse across q-tiles.

typedef __bf16 bf16;
typedef __bf16 bf16x8 __attribute__((ext_vector_type(8)));
typedef __bf16 bf16x4 __attribute__((ext_vector_type(4)));
typedef float floatx4 __attribute__((ext_vector_type(4)));

#define MFMA16(a, b, c) __builtin_amdgcn_mfma_f32_16x16x32_bf16((a), (b), (c), 0, 0, 0)

#define LOG2E 1.4426950408889634f

// K-tile LDS chunk swizzle: g bits = (b0^b3, b1^b4, b2^b3) of the 6-bit key.
// Chosen so the PERMUTED S-MFMA fragment reads (key = 8*(lcol>>2)+(lcol&3)+
// 4*(j&1)+32*(j>>1)) spread uniformly over all 8 16B bank-groups.
#define GK(key) ((((key) ^ ((key) >> 3)) & 3) | (((((key) >> 2) ^ ((key) >> 3)) & 1) << 2))

__device__ __forceinline__ void gld16(const bf16* g, bf16* l) {
    __builtin_amdgcn_global_load_lds(
        (const __attribute__((address_space(1))) unsigned int*)g,
        (__attribute__((address_space(3))) unsigned int*)l, 16, 0, 0);
}

// ---------------- prep kernels ----------------
__global__ __launch_bounds__(256) void cvt_kernel(const float* __restrict__ x,
                                                  bf16* __restrict__ y, int n4) {
    int i = blockIdx.x * blockDim.x + threadIdx.x;
    if (i >= n4) return;
    float4 v = ((const float4*)x)[i];
    bf16x4 o;
    o.x = (bf16)v.x; o.y = (bf16)v.y; o.z = (bf16)v.z; o.w = (bf16)v.w;
    ((bf16x4*)y)[i] = o;
}

// bias combine with log2e fold (softmax runs in log2 domain)
__global__ __launch_bounds__(256) void combine_kernel(const float* __restrict__ a,
                                                      const float* __restrict__ b,
                                                      bf16* __restrict__ y, int n4) {
    int i = blockIdx.x * blockDim.x + threadIdx.x;
    if (i >= n4) return;
    float4 va = ((const float4*)a)[i];
    float4 vb = ((const float4*)b)[i];
    bf16x4 o;
    o.x = (bf16)((va.x + vb.x) * LOG2E); o.y = (bf16)((va.y + vb.y) * LOG2E);
    o.z = (bf16)((va.z + vb.z) * LOG2E); o.w = (bf16)((va.w + vb.w) * LOG2E);
    ((bf16x4*)y)[i] = o;
}

__global__ __launch_bounds__(256) void mask_kernel(const int* __restrict__ m,
                                                   float* __restrict__ om, int n) {
    int i = blockIdx.x * blockDim.x + threadIdx.x;
    if (i < n) om[i] = m[i] ? 0.f : 1.f;
}

// ---------------- QKV GEMM ----------------
__global__ __launch_bounds__(256) void qkv_gemm(
    const bf16* __restrict__ X, const bf16* __restrict__ W,
    const float* __restrict__ qbias, const float* __restrict__ vbias,
    bf16* __restrict__ qbuf, bf16* __restrict__ kbuf, bf16* __restrict__ vbuf) {
    __shared__ __align__(16) bf16 Al[128 * 32];
    __shared__ __align__(16) bf16 Bl[128 * 32];

    int tid = threadIdx.x, lane = tid & 63, w = tid >> 6;
    int quad = lane >> 4, lcol = lane & 15;
    int bx = blockIdx.x;
    int by = blockIdx.y;
    int wr = w >> 1, wc = w & 1;

    floatx4 z4 = {0.f, 0.f, 0.f, 0.f};
    floatx4 acc[4][4];
    for (int i = 0; i < 4; ++i)
        for (int j = 0; j < 4; ++j) acc[i][j] = z4;

    const bf16* Ag = X + (size_t)by * 128 * 1024;
    const bf16* Bg = W + (size_t)bx * 128 * 1024;

    for (int kt = 0; kt < 32; ++kt) {
        int k0 = kt * 32;
        __syncthreads();
        for (int j = 0; j < 2; ++j) {
            int c = (w * 2 + j) * 64 + lane;
            int row = c >> 2;
            int dc = (c & 3) ^ (row & 3);
            gld16(Ag + (size_t)row * 1024 + k0 + dc * 8, &Al[(w * 2 + j) * 64 * 8]);
        }
        for (int j = 0; j < 2; ++j) {
            int c = (w * 2 + j) * 64 + lane;
            int row = c >> 2;
            int dc = (c & 3) ^ (row & 3);
            gld16(Bg + (size_t)row * 1024 + k0 + dc * 8, &Bl[(w * 2 + j) * 64 * 8]);
        }
        __syncthreads();

        bf16x8 af[4], bfr[4];
        for (int i = 0; i < 4; ++i) {
            int r = wr * 64 + i * 16 + lcol;
            af[i] = *(const bf16x8*)&Al[r * 32 + ((quad ^ (r & 3)) * 8)];
        }
        for (int j = 0; j < 4; ++j) {
            int r = wc * 64 + j * 16 + lcol;
            bfr[j] = *(const bf16x8*)&Bl[r * 32 + ((quad ^ (r & 3)) * 8)];
        }
        for (int i = 0; i < 4; ++i)
            for (int j = 0; j < 4; ++j) acc[i][j] = MFMA16(af[i], bfr[j], acc[i][j]);
    }

    int col0 = bx * 128 + wc * 64;
    int row0 = by * 128 + wr * 64;
    int seg = col0 >> 10;

    for (int i = 0; i < 4; ++i) {
        int m0 = row0 + i * 16 + quad * 4;
        int bb = m0 >> 10, n0 = m0 & 1023;
        for (int j = 0; j < 4; ++j) {
            int o = col0 + j * 16 + lcol;
            if (seg == 0) {
                int hh = o >> 6, d = o & 63;
                float qb = qbias[o];
                for (int r = 0; r < 4; ++r) {
                    // q scale 1/8 with log2e folded (softmax in log2 domain)
                    float v = (acc[i][j][r] + qb) * (0.125f * LOG2E);
                    qbuf[((size_t)((bb * 16 + hh) * 1024 + n0 + r)) * 64 + d] = (bf16)v;
                }
            } else if (seg == 1) {
                int o2 = o - 1024;
                int hh = o2 >> 6, d = o2 & 63;
                for (int r = 0; r < 4; ++r) {
                    kbuf[((size_t)((bb * 16 + hh) * 1024 + n0 + r)) * 64 + d] = (bf16)acc[i][j][r];
                }
            } else {
                int o2 = o - 2048;
                int hh = o2 >> 6, d = o2 & 63;
                float vbv = vbias[o2];
                bf16x4 pk;
                pk.x = (bf16)(acc[i][j][0] + vbv);
                pk.y = (bf16)(acc[i][j][1] + vbv);
                pk.z = (bf16)(acc[i][j][2] + vbv);
                pk.w = (bf16)(acc[i][j][3] + vbv);
                *(bf16x4*)&vbuf[((size_t)((bb * 16 + hh) * 64 + d)) * 1024 + n0] = pk;
            }
        }
    }
}

// ---------------- flash attention ----------------
// Block = (b, h, 128 q rows), 4 waves; wave owns 2 independent 16-row strips.
// MAX-FREE softmax in log2 domain: |s| <= ~15 bits -> exp2 always in range.
// S^T = MFMA(A=K permuted rows, B=Q, C=bias). The key permutation
//   key(j, m) = 32*(j>>1) + 8*(m>>2) + 4*(j&1) + (m&3)
// makes the C-layout output (lane quad, reg r) hold keys 8*quad+e directly,
// so (p[s][0][*], p[s][1][*]) packs straight into the O-MFMA B-fragment:
// no P LDS round-trip, no cross-lane ops. O^T = MFMA(A=Vt, B=P).
// LDS = 32KB (K/V double buffer) -> 5 blocks/CU; all 1024 blocks co-resident.
__global__ __launch_bounds__(256, 5) void flash_attn(
    const bf16* __restrict__ qbuf, const bf16* __restrict__ kbuf,
    const bf16* __restrict__ vbuf, const bf16* __restrict__ bias,
    const float* __restrict__ om, float* __restrict__ out) {
    __shared__ __align__(16) bf16 Kl[2][64 * 64];
    __shared__ __align__(16) bf16 Vl[2][64 * 64];

    int tid = threadIdx.x, lane = tid & 63, w = tid >> 6;
    int quad = lane >> 4, lcol = lane & 15;
    int bx = blockIdx.x;
    // XCD-aware decode (XCD = bx % 8 under round-robin dispatch): each XCD owns
    // 16 (h,q2) pairs; the 8 batch-blocks of a pair run back-to-back on one XCD
    // so the 256KB bias tile is L2-resident for its 8 reuses, and each (b,h)
    // K/V tile is L2-reused across the 8 q2 pairs of the same h.
    int xcd = bx & 7, slot = bx >> 3;
    int pair = xcd * 16 + (slot >> 3);
    int b = slot & 7;
    int h = pair >> 3, q2 = pair & 7;

    const bf16* kb = kbuf + ((size_t)((b * 16 + h) * 1024)) * 64;
    const bf16* vb = vbuf + ((size_t)((b * 16 + h) * 64)) * 1024;  // [d][n]
    const float* omb = om + b * 1024;

    int qrow[2] = {q2 * 128 + w * 16, q2 * 128 + 64 + w * 16};
    bf16x8 qf[2][2];
    const bf16* bb[2];
#pragma unroll
    for (int s = 0; s < 2; ++s) {
        const bf16* qp = qbuf + ((size_t)((b * 16 + h) * 1024 + qrow[s] + lcol)) * 64;
        qf[s][0] = *(const bf16x8*)(qp + quad * 8);
        qf[s][1] = *(const bf16x8*)(qp + 32 + quad * 8);
        bb[s] = bias + (size_t)h * 1024 * 1024 + (size_t)(qrow[s] + lcol) * 1024;
    }

    floatx4 z4 = {0.f, 0.f, 0.f, 0.f};
    floatx4 oacc[2][4];
    float lrun[2] = {0.f, 0.f};
#pragma unroll
    for (int s = 0; s < 2; ++s)
        for (int j = 0; j < 4; ++j) oacc[s][j] = z4;

    // stage tile 0 into buffer 0
#pragma unroll
    for (int j = 0; j < 2; ++j) {
        int c = (w * 2 + j) * 64 + lane;
        int key = c >> 3;
        int dc = (c & 7) ^ GK(key);
        gld16(kb + (size_t)key * 64 + dc * 8, &Kl[0][(w * 2 + j) * 512]);
    }
#pragma unroll
    for (int j = 0; j < 2; ++j) {
        int c = (w * 2 + j) * 64 + lane;
        int d = c >> 3;
        int kc = (c & 7) ^ (d & 7);
        gld16(vb + (size_t)d * 1024 + kc * 8, &Vl[0][(w * 2 + j) * 512]);
    }

    // prefetch bias (per strip, bf16) + om (f32, shared) for tile 0, in the
    // PERMUTED key order matching the S-MFMA C layout.
    bf16x4 bf_[2][4];
    floatx4 of_[4];
#pragma unroll
    for (int j = 0; j < 4; ++j) {
        int kboff = ((j >> 1) << 5) + (quad << 3) + ((j & 1) << 2);
#pragma unroll
        for (int s = 0; s < 2; ++s) bf_[s][j] = *(const bf16x4*)(bb[s] + kboff);
        of_[j] = *(const floatx4*)(omb + kboff);
    }

    for (int kt = 0; kt < 16; ++kt) {
        int k0 = kt * 64;
        int cur = kt & 1, nxt = cur ^ 1;
        __syncthreads();  // buf[cur] staged; buf[nxt] free

        // stage tile kt+1 into buf[nxt]
        if (kt < 15) {
            int k1 = k0 + 64;
#pragma unroll
            for (int j = 0; j < 2; ++j) {
                int c = (w * 2 + j) * 64 + lane;
                int key = c >> 3;
                int dc = (c & 7) ^ GK(key);
                gld16(kb + (size_t)(k1 + key) * 64 + dc * 8, &Kl[nxt][(w * 2 + j) * 512]);
            }
#pragma unroll
            for (int j = 0; j < 2; ++j) {
                int c = (w * 2 + j) * 64 + lane;
                int d = c >> 3;
                int kc = (c & 7) ^ (d & 7);
                gld16(vb + (size_t)d * 1024 + k1 + kc * 8, &Vl[nxt][(w * 2 + j) * 512]);
            }
        }
        int kp = (kt < 15) ? k0 + 64 : 0;
        bf16x4 bn[2][4];
        floatx4 on[4];
#pragma unroll
        for (int j = 0; j < 4; ++j) {
            int kboff = ((j >> 1) << 5) + (quad << 3) + ((j & 1) << 2);
#pragma unroll
            for (int s = 0; s < 2; ++s) bn[s][j] = *(const bf16x4*)(bb[s] + kp + kboff);
            on[j] = *(const floatx4*)(omb + kp + kboff);
        }

        // S^T + bias = MFMA(A=K permuted, B=Q, C=bias); K frags shared across strips
        floatx4 sacc[2][4];
#pragma unroll
        for (int j = 0; j < 4; ++j) {
            int key = ((j >> 1) << 5) + ((lcol >> 2) << 3) + ((j & 1) << 2) + (lcol & 3);
            int gk = GK(key);
            bf16x8 kf0 = *(const bf16x8*)&Kl[cur][key * 64 + ((quad ^ gk) * 8)];
            bf16x8 kf1 = *(const bf16x8*)&Kl[cur][key * 64 + (((4 + quad) ^ gk) * 8)];
#pragma unroll
            for (int s = 0; s < 2; ++s) {
                floatx4 binit;
                binit[0] = (float)bf_[s][j][0]; binit[1] = (float)bf_[s][j][1];
                binit[2] = (float)bf_[s][j][2]; binit[3] = (float)bf_[s][j][3];
                sacc[s][j] = MFMA16(kf0, qf[s][0], binit);
                sacc[s][j] = MFMA16(kf1, qf[s][1], sacc[s][j]);
            }
        }

        // p = exp2((s+b)*om + c); accumulate per-lane lrun partials (no shuffles)
        float p[2][4][4];
#pragma unroll
        for (int s = 0; s < 2; ++s) {
            float psum = 0.f;
#pragma unroll
            for (int j = 0; j < 4; ++j)
#pragma unroll
                for (int r = 0; r < 4; ++r) {
                    float sv = fmaf(sacc[s][j][r], of_[j][r], 1e-8f * LOG2E);
                    p[s][j][r] = __builtin_amdgcn_exp2f(sv);
                    psum += p[s][j][r];
                }
            lrun[s] += psum;
        }

        // pack P straight into B-operand fragments (keys already lane-local):
        // pf0 = keys 8q+0..7 = (p[s][0][0..3], p[s][1][0..3]); pf1 = +32.
        bf16x8 pf0[2], pf1[2];
#pragma unroll
        for (int s = 0; s < 2; ++s) {
            pf0[s][0] = (bf16)p[s][0][0]; pf0[s][1] = (bf16)p[s][0][1];
            pf0[s][2] = (bf16)p[s][0][2]; pf0[s][3] = (bf16)p[s][0][3];
            pf0[s][4] = (bf16)p[s][1][0]; pf0[s][5] = (bf16)p[s][1][1];
            pf0[s][6] = (bf16)p[s][1][2]; pf0[s][7] = (bf16)p[s][1][3];
            pf1[s][0] = (bf16)p[s][2][0]; pf1[s][1] = (bf16)p[s][2][1];
            pf1[s][2] = (bf16)p[s][2][2]; pf1[s][3] = (bf16)p[s][2][3];
            pf1[s][4] = (bf16)p[s][3][0]; pf1[s][5] = (bf16)p[s][3][1];
            pf1[s][6] = (bf16)p[s][3][2]; pf1[s][7] = (bf16)p[s][3][3];
        }

        // O^T += Vt P^T; V frags shared across strips
#pragma unroll
        for (int jd = 0; jd < 4; ++jd) {
            int dd = jd * 16 + lcol;
            bf16x8 vf0 = *(const bf16x8*)&Vl[cur][dd * 64 + ((quad ^ (dd & 7)) * 8)];
            bf16x8 vf1 = *(const bf16x8*)&Vl[cur][dd * 64 + (((4 + quad) ^ (dd & 7)) * 8)];
            oacc[0][jd] = MFMA16(vf0, pf0[0], oacc[0][jd]);
            oacc[1][jd] = MFMA16(vf0, pf0[1], oacc[1][jd]);
            oacc[0][jd] = MFMA16(vf1, pf1[0], oacc[0][jd]);
            oacc[1][jd] = MFMA16(vf1, pf1[1], oacc[1][jd]);
        }

        // rotate bias/om prefetch
#pragma unroll
        for (int j = 0; j < 4; ++j) {
#pragma unroll
            for (int s = 0; s < 2; ++s) bf_[s][j] = bn[s][j];
            of_[j] = on[j];
        }
    }

    // epilogue: reduce lrun across quads (once), normalize, store
#pragma unroll
    for (int s = 0; s < 2; ++s) {
        float l = lrun[s];
        l += __shfl_xor(l, 16);
        l += __shfl_xor(l, 32);
        float linv = 1.f / l;
#pragma unroll
        for (int jd = 0; jd < 4; ++jd) {
            float4 st;
            st.x = oacc[s][jd][0] * linv;
            st.y = oacc[s][jd][1] * linv;
            st.z = oacc[s][jd][2] * linv;
            st.w = oacc[s][jd][3] * linv;
            *(float4*)&out[((size_t)(b * 1024 + qrow[s] + lcol)) * 1024 + h * 64 + jd * 16 + quad * 4] = st;
        }
    }
}

// ---------------- launch ----------------
extern "C" void kernel_launch(void* const* d_in, const int* in_sizes, int n_in,
                              void* d_out, int out_size, void* d_ws, size_t ws_size,
                              hipStream_t stream) {
    const float* hs   = (const float*)d_in[0];
    const float* qkvw = (const float*)d_in[1];
    const float* qb   = (const float*)d_in[2];
    const float* vbi  = (const float*)d_in[3];
    const float* rel  = (const float*)d_in[4];
    const float* rel2 = (const float*)d_in[5];
    const int*   msk  = (const int*)d_in[6];
    float* out = (float*)d_out;

    char* w = (char*)d_ws;
    bf16* Xb = (bf16*)w;  w += (size_t)8388608 * 2;
    bf16* Wb = (bf16*)w;  w += (size_t)3145728 * 2;
    bf16* Bb = (bf16*)w;  w += (size_t)16777216 * 2;
    bf16* Qb = (bf16*)w;  w += (size_t)8388608 * 2;
    bf16* Kb = (bf16*)w;  w += (size_t)8388608 * 2;
    bf16* Vb = (bf16*)w;  w += (size_t)8388608 * 2;
    float* OM = (float*)w; w += (size_t)8192 * 4;

    cvt_kernel<<<8388608 / 4 / 256, 256, 0, stream>>>(hs, Xb, 8388608 / 4);
    cvt_kernel<<<3145728 / 4 / 256, 256, 0, stream>>>(qkvw, Wb, 3145728 / 4);
    combine_kernel<<<16777216 / 4 / 256, 256, 0, stream>>>(rel, rel2, Bb, 16777216 / 4);
    mask_kernel<<<32, 256, 0, stream>>>(msk, OM, 8192);
    qkv_gemm<<<dim3(24, 64), 256, 0, stream>>>(Xb, Wb, qb, vbi, Qb, Kb, Vb);
    flash_attn<<<1024, 256, 0, stream>>>(Qb, Kb, Vb, Bb, OM, out);
}

// Round 3
// 340.310 us; speedup vs baseline: 1.6168x; 1.6168x over previous
//
#include <hip/hip_runtime.h>

// LayoutLMv2 self-attention, MI355X.  B=8 N=1024 H=16 D=64.
// fp32->bf16 converts, bias combine (log2e folded), mask->u64 bitmasks, bf16 MFMA
// QKV GEMM (q-scale*log2e folded), flash attention: 1 q-strip/wave (64-row
// blocks), MAX-FREE log2-domain softmax, bias folded into MFMA C-operand,
// ZERO LDS round-trip for P (permuted-key S-MFMA output IS the O-MFMA
// B-fragment), mask applied via packed bitmask select (no f32 om loads).
// LDS = 32KB (K/V dbuf) + launch_bounds(256,4): 4 blocks/CU, 16 waves/CU,
// ~100 VGPR demand vs 128 cap -> NO scratch spill (round-2 lesson).

typedef __bf16 bf16;
typedef __bf16 bf16x8 __attribute__((ext_vector_type(8)));
typedef __bf16 bf16x4 __attribute__((ext_vector_type(4)));
typedef float floatx4 __attribute__((ext_vector_type(4)));

#define MFMA16(a, b, c) __builtin_amdgcn_mfma_f32_16x16x32_bf16((a), (b), (c), 0, 0, 0)

#define LOG2E 1.4426950408889634f

// K-tile LDS chunk swizzle: g bits = (b0^b3, b1^b4, b2^b3) of the 6-bit key.
// Spreads the PERMUTED S-MFMA fragment reads uniformly over all 8 16B groups.
#define GK(key) ((((key) ^ ((key) >> 3)) & 3) | (((((key) >> 2) ^ ((key) >> 3)) & 1) << 2))

__device__ __forceinline__ void gld16(const bf16* g, bf16* l) {
    __builtin_amdgcn_global_load_lds(
        (const __attribute__((address_space(1))) unsigned int*)g,
        (__attribute__((address_space(3))) unsigned int*)l, 16, 0, 0);
}

// ---------------- prep kernels ----------------
__global__ __launch_bounds__(256) void cvt_kernel(const float* __restrict__ x,
                                                  bf16* __restrict__ y, int n4) {
    int i = blockIdx.x * blockDim.x + threadIdx.x;
    if (i >= n4) return;
    float4 v = ((const float4*)x)[i];
    bf16x4 o;
    o.x = (bf16)v.x; o.y = (bf16)v.y; o.z = (bf16)v.z; o.w = (bf16)v.w;
    ((bf16x4*)y)[i] = o;
}

// bias combine with log2e fold (softmax runs in log2 domain)
__global__ __launch_bounds__(256) void combine_kernel(const float* __restrict__ a,
                                                      const float* __restrict__ b,
                                                      bf16* __restrict__ y, int n4) {
    int i = blockIdx.x * blockDim.x + threadIdx.x;
    if (i >= n4) return;
    float4 va = ((const float4*)a)[i];
    float4 vb = ((const float4*)b)[i];
    bf16x4 o;
    o.x = (bf16)((va.x + vb.x) * LOG2E); o.y = (bf16)((va.y + vb.y) * LOG2E);
    o.z = (bf16)((va.z + vb.z) * LOG2E); o.w = (bf16)((va.w + vb.w) * LOG2E);
    ((bf16x4*)y)[i] = o;
}

// packed keep-bitmask: om64[b*16 + t] bit k = (mask[b, t*64+k] == 0)
__global__ __launch_bounds__(256) void mask64_kernel(const int* __restrict__ m,
                                                     unsigned long long* __restrict__ om64) {
    int tid = blockIdx.x * blockDim.x + threadIdx.x;
    int gw = tid >> 6, lane = tid & 63;  // gw = b*16 + t, 0..127
    bool keep = (m[gw * 64 + lane] == 0);
    unsigned long long bal = __ballot(keep);
    if (lane == 0) om64[gw] = bal;
}

// ---------------- QKV GEMM ----------------
__global__ __launch_bounds__(256) void qkv_gemm(
    const bf16* __restrict__ X, const bf16* __restrict__ W,
    const float* __restrict__ qbias, const float* __restrict__ vbias,
    bf16* __restrict__ qbuf, bf16* __restrict__ kbuf, bf16* __restrict__ vbuf) {
    __shared__ __align__(16) bf16 Al[128 * 32];
    __shared__ __align__(16) bf16 Bl[128 * 32];

    int tid = threadIdx.x, lane = tid & 63, w = tid >> 6;
    int quad = lane >> 4, lcol = lane & 15;
    int bx = blockIdx.x;
    int by = blockIdx.y;
    int wr = w >> 1, wc = w & 1;

    floatx4 z4 = {0.f, 0.f, 0.f, 0.f};
    floatx4 acc[4][4];
    for (int i = 0; i < 4; ++i)
        for (int j = 0; j < 4; ++j) acc[i][j] = z4;

    const bf16* Ag = X + (size_t)by * 128 * 1024;
    const bf16* Bg = W + (size_t)bx * 128 * 1024;

    for (int kt = 0; kt < 32; ++kt) {
        int k0 = kt * 32;
        __syncthreads();
        for (int j = 0; j < 2; ++j) {
            int c = (w * 2 + j) * 64 + lane;
            int row = c >> 2;
            int dc = (c & 3) ^ (row & 3);
            gld16(Ag + (size_t)row * 1024 + k0 + dc * 8, &Al[(w * 2 + j) * 64 * 8]);
        }
        for (int j = 0; j < 2; ++j) {
            int c = (w * 2 + j) * 64 + lane;
            int row = c >> 2;
            int dc = (c & 3) ^ (row & 3);
            gld16(Bg + (size_t)row * 1024 + k0 + dc * 8, &Bl[(w * 2 + j) * 64 * 8]);
        }
        __syncthreads();

        bf16x8 af[4], bfr[4];
        for (int i = 0; i < 4; ++i) {
            int r = wr * 64 + i * 16 + lcol;
            af[i] = *(const bf16x8*)&Al[r * 32 + ((quad ^ (r & 3)) * 8)];
        }
        for (int j = 0; j < 4; ++j) {
            int r = wc * 64 + j * 16 + lcol;
            bfr[j] = *(const bf16x8*)&Bl[r * 32 + ((quad ^ (r & 3)) * 8)];
        }
        for (int i = 0; i < 4; ++i)
            for (int j = 0; j < 4; ++j) acc[i][j] = MFMA16(af[i], bfr[j], acc[i][j]);
    }

    int col0 = bx * 128 + wc * 64;
    int row0 = by * 128 + wr * 64;
    int seg = col0 >> 10;

    for (int i = 0; i < 4; ++i) {
        int m0 = row0 + i * 16 + quad * 4;
        int bb = m0 >> 10, n0 = m0 & 1023;
        for (int j = 0; j < 4; ++j) {
            int o = col0 + j * 16 + lcol;
            if (seg == 0) {
                int hh = o >> 6, d = o & 63;
                float qb = qbias[o];
                for (int r = 0; r < 4; ++r) {
                    // q scale 1/8 with log2e folded (softmax in log2 domain)
                    float v = (acc[i][j][r] + qb) * (0.125f * LOG2E);
                    qbuf[((size_t)((bb * 16 + hh) * 1024 + n0 + r)) * 64 + d] = (bf16)v;
                }
            } else if (seg == 1) {
                int o2 = o - 1024;
                int hh = o2 >> 6, d = o2 & 63;
                for (int r = 0; r < 4; ++r) {
                    kbuf[((size_t)((bb * 16 + hh) * 1024 + n0 + r)) * 64 + d] = (bf16)acc[i][j][r];
                }
            } else {
                int o2 = o - 2048;
                int hh = o2 >> 6, d = o2 & 63;
                float vbv = vbias[o2];
                bf16x4 pk;
                pk.x = (bf16)(acc[i][j][0] + vbv);
                pk.y = (bf16)(acc[i][j][1] + vbv);
                pk.z = (bf16)(acc[i][j][2] + vbv);
                pk.w = (bf16)(acc[i][j][3] + vbv);
                *(bf16x4*)&vbuf[((size_t)((bb * 16 + hh) * 64 + d)) * 1024 + n0] = pk;
            }
        }
    }
}

// ---------------- flash attention ----------------
// Block = (b, h, 64 q rows), 4 waves; wave owns ONE 16-row strip.
// S^T = MFMA(A=K permuted rows, B=Q, C=bias). The key permutation
//   key(j, m) = 32*(j>>1) + 8*(m>>2) + 4*(j&1) + (m&3)
// makes the C-layout output (lane quad, reg r) hold keys 8*quad+e directly,
// so (p[0][*], p[1][*]) packs straight into the O-MFMA B-fragment: no P LDS
// round-trip, no cross-lane ops. Mask via packed u64 bitmask select
// (masked key -> sv=0 -> p=1.0 == exp(1e-8) within bf16). O^T = MFMA(A=Vt,B=P).
__global__ __launch_bounds__(256, 4) void flash_attn(
    const bf16* __restrict__ qbuf, const bf16* __restrict__ kbuf,
    const bf16* __restrict__ vbuf, const bf16* __restrict__ bias,
    const unsigned long long* __restrict__ om64, float* __restrict__ out) {
    __shared__ __align__(16) bf16 Kl[2][64 * 64];
    __shared__ __align__(16) bf16 Vl[2][64 * 64];

    int tid = threadIdx.x, lane = tid & 63, w = tid >> 6;
    int quad = lane >> 4, lcol = lane & 15;
    int bx = blockIdx.x;
    // XCD-aware decode (XCD = bx % 8): each XCD owns 2 heads x 16 q-tiles;
    // the 8 batch-blocks of a (h,q4) run back-to-back (bias tile 128KB x8
    // L2 reuse); K/V of (b,h) reused across the 16 q4 of that h (~2MB set).
    int xcd = bx & 7, slot = bx >> 3;
    int pair = xcd * 32 + (slot >> 3);  // 0..255
    int b = slot & 7;
    int h = pair >> 4, q4 = pair & 15;

    const bf16* kb = kbuf + ((size_t)((b * 16 + h) * 1024)) * 64;
    const bf16* vb = vbuf + ((size_t)((b * 16 + h) * 64)) * 1024;  // [d][n]
    const unsigned long long* mp = om64 + b * 16;

    int qrow = q4 * 64 + w * 16;
    const bf16* qp = qbuf + ((size_t)((b * 16 + h) * 1024 + qrow + lcol)) * 64;
    bf16x8 qf0 = *(const bf16x8*)(qp + quad * 8);
    bf16x8 qf1 = *(const bf16x8*)(qp + 32 + quad * 8);
    const bf16* bb = bias + (size_t)h * 1024 * 1024 + (size_t)(qrow + lcol) * 1024;

    floatx4 z4 = {0.f, 0.f, 0.f, 0.f};
    floatx4 oacc[4] = {z4, z4, z4, z4};
    float lrun = 0.f;

    // stage tile 0 into buffer 0
#pragma unroll
    for (int j = 0; j < 2; ++j) {
        int c = (w * 2 + j) * 64 + lane;
        int key = c >> 3;
        int dc = (c & 7) ^ GK(key);
        gld16(kb + (size_t)key * 64 + dc * 8, &Kl[0][(w * 2 + j) * 512]);
    }
#pragma unroll
    for (int j = 0; j < 2; ++j) {
        int c = (w * 2 + j) * 64 + lane;
        int d = c >> 3;
        int kc = (c & 7) ^ (d & 7);
        gld16(vb + (size_t)d * 1024 + kc * 8, &Vl[0][(w * 2 + j) * 512]);
    }

    // prefetch bias (bf16, PERMUTED key order matching S-MFMA C layout) + mask
    bf16x4 bf_[4];
#pragma unroll
    for (int j = 0; j < 4; ++j) {
        int kboff = ((j >> 1) << 5) + (quad << 3) + ((j & 1) << 2);
        bf_[j] = *(const bf16x4*)(bb + kboff);
    }
    unsigned long long mcur = mp[0];

    for (int kt = 0; kt < 16; ++kt) {
        int k0 = kt * 64;
        int cur = kt & 1, nxt = cur ^ 1;
        __syncthreads();  // buf[cur] staged; buf[nxt] free

        // stage tile kt+1 into buf[nxt]
        if (kt < 15) {
            int k1 = k0 + 64;
#pragma unroll
            for (int j = 0; j < 2; ++j) {
                int c = (w * 2 + j) * 64 + lane;
                int key = c >> 3;
                int dc = (c & 7) ^ GK(key);
                gld16(kb + (size_t)(k1 + key) * 64 + dc * 8, &Kl[nxt][(w * 2 + j) * 512]);
            }
#pragma unroll
            for (int j = 0; j < 2; ++j) {
                int c = (w * 2 + j) * 64 + lane;
                int d = c >> 3;
                int kc = (c & 7) ^ (d & 7);
                gld16(vb + (size_t)d * 1024 + k1 + kc * 8, &Vl[nxt][(w * 2 + j) * 512]);
            }
        }
        int kp = (kt < 15) ? k0 + 64 : 0;
        bf16x4 bn[4];
#pragma unroll
        for (int j = 0; j < 4; ++j) {
            int kboff = ((j >> 1) << 5) + (quad << 3) + ((j & 1) << 2);
            bn[j] = *(const bf16x4*)(bb + kp + kboff);
        }
        unsigned long long mn = mp[(kt < 15) ? kt + 1 : 0];

        // S^T + bias = MFMA(A=K permuted, B=Q, C=bias)
        floatx4 sacc[4];
#pragma unroll
        for (int j = 0; j < 4; ++j) {
            int key = ((j >> 1) << 5) + ((lcol >> 2) << 3) + ((j & 1) << 2) + (lcol & 3);
            int gk = GK(key);
            bf16x8 kf0 = *(const bf16x8*)&Kl[cur][key * 64 + ((quad ^ gk) * 8)];
            bf16x8 kf1 = *(const bf16x8*)&Kl[cur][key * 64 + (((4 + quad) ^ gk) * 8)];
            floatx4 binit;
            binit[0] = (float)bf_[j][0]; binit[1] = (float)bf_[j][1];
            binit[2] = (float)bf_[j][2]; binit[3] = (float)bf_[j][3];
            sacc[j] = MFMA16(kf0, qf0, binit);
            sacc[j] = MFMA16(kf1, qf1, sacc[j]);
        }

        // mask-select + p = exp2(sv); per-lane lrun partials (no shuffles).
        // this lane's 16 keys are bits {8q..8q+7, 32+8q..32+8q+7} of mcur,
        // packed so element (j,r) is bit j*4+r of mbits.
        unsigned int mbits = ((unsigned int)(mcur >> (8 * quad)) & 0xffu) |
                             (((unsigned int)(mcur >> (32 + 8 * quad)) & 0xffu) << 8);
        float p[4][4];
        float psum = 0.f;
#pragma unroll
        for (int j = 0; j < 4; ++j)
#pragma unroll
            for (int r = 0; r < 4; ++r) {
                float sv = ((mbits >> (j * 4 + r)) & 1u) ? sacc[j][r] : 0.f;
                p[j][r] = __builtin_amdgcn_exp2f(sv);
                psum += p[j][r];
            }
        lrun += psum;

        // pack P straight into B-operand fragments (keys already lane-local):
        // pf0 = keys 8q+0..7 = (p[0][0..3], p[1][0..3]); pf1 = +32.
        bf16x8 pf0, pf1;
        pf0[0] = (bf16)p[0][0]; pf0[1] = (bf16)p[0][1];
        pf0[2] = (bf16)p[0][2]; pf0[3] = (bf16)p[0][3];
        pf0[4] = (bf16)p[1][0]; pf0[5] = (bf16)p[1][1];
        pf0[6] = (bf16)p[1][2]; pf0[7] = (bf16)p[1][3];
        pf1[0] = (bf16)p[2][0]; pf1[1] = (bf16)p[2][1];
        pf1[2] = (bf16)p[2][2]; pf1[3] = (bf16)p[2][3];
        pf1[4] = (bf16)p[3][0]; pf1[5] = (bf16)p[3][1];
        pf1[6] = (bf16)p[3][2]; pf1[7] = (bf16)p[3][3];

        // O^T += Vt P^T
#pragma unroll
        for (int jd = 0; jd < 4; ++jd) {
            int dd = jd * 16 + lcol;
            bf16x8 vf0 = *(const bf16x8*)&Vl[cur][dd * 64 + ((quad ^ (dd & 7)) * 8)];
            bf16x8 vf1 = *(const bf16x8*)&Vl[cur][dd * 64 + (((4 + quad) ^ (dd & 7)) * 8)];
            oacc[jd] = MFMA16(vf0, pf0, oacc[jd]);
            oacc[jd] = MFMA16(vf1, pf1, oacc[jd]);
        }

        // rotate bias/mask prefetch
#pragma unroll
        for (int j = 0; j < 4; ++j) bf_[j] = bn[j];
        mcur = mn;
    }

    // epilogue: reduce lrun across quads (once), normalize, store
    float l = lrun;
    l += __shfl_xor(l, 16);
    l += __shfl_xor(l, 32);
    float linv = 1.f / l;
#pragma unroll
    for (int jd = 0; jd < 4; ++jd) {
        float4 st;
        st.x = oacc[jd][0] * linv;
        st.y = oacc[jd][1] * linv;
        st.z = oacc[jd][2] * linv;
        st.w = oacc[jd][3] * linv;
        *(float4*)&out[((size_t)(b * 1024 + qrow + lcol)) * 1024 + h * 64 + jd * 16 + quad * 4] = st;
    }
}

// ---------------- launch ----------------
extern "C" void kernel_launch(void* const* d_in, const int* in_sizes, int n_in,
                              void* d_out, int out_size, void* d_ws, size_t ws_size,
                              hipStream_t stream) {
    const float* hs   = (const float*)d_in[0];
    const float* qkvw = (const float*)d_in[1];
    const float* qb   = (const float*)d_in[2];
    const float* vbi  = (const float*)d_in[3];
    const float* rel  = (const float*)d_in[4];
    const float* rel2 = (const float*)d_in[5];
    const int*   msk  = (const int*)d_in[6];
    float* out = (float*)d_out;

    char* w = (char*)d_ws;
    bf16* Xb = (bf16*)w;  w += (size_t)8388608 * 2;
    bf16* Wb = (bf16*)w;  w += (size_t)3145728 * 2;
    bf16* Bb = (bf16*)w;  w += (size_t)16777216 * 2;
    bf16* Qb = (bf16*)w;  w += (size_t)8388608 * 2;
    bf16* Kb = (bf16*)w;  w += (size_t)8388608 * 2;
    bf16* Vb = (bf16*)w;  w += (size_t)8388608 * 2;
    unsigned long long* OM = (unsigned long long*)w; w += (size_t)128 * 8;

    cvt_kernel<<<8388608 / 4 / 256, 256, 0, stream>>>(hs, Xb, 8388608 / 4);
    cvt_kernel<<<3145728 / 4 / 256, 256, 0, stream>>>(qkvw, Wb, 3145728 / 4);
    combine_kernel<<<16777216 / 4 / 256, 256, 0, stream>>>(rel, rel2, Bb, 16777216 / 4);
    mask64_kernel<<<32, 256, 0, stream>>>(msk, OM);
    qkv_gemm<<<dim3(24, 64), 256, 0, stream>>>(Xb, Wb, qb, vbi, Qb, Kb, Vb);
    flash_attn<<<2048, 256, 0, stream>>>(Qb, Kb, Vb, Bb, OM, out);
}